// Round 6
// baseline (301.766 us; speedup 1.0000x reference)
//
#include <hip/hip_runtime.h>
#include <stdint.h>

#define NLAYERS 3
#define NQ 8
#define DIM 256          // 2^NQ
#define BATCH 131072

typedef float  f32x4  __attribute__((ext_vector_type(4)));
typedef __bf16 bf16x8 __attribute__((ext_vector_type(8)));

__device__ __forceinline__ unsigned short f2bf(float f){
    union { float f; uint32_t u; } v; v.f = f;
    uint32_t u = v.u;
    u += 0x7fffu + ((u >> 16) & 1u);   // round-to-nearest-even
    return (unsigned short)(u >> 16);
}

__device__ __forceinline__ float2 cmul(float2 a, float2 b){
    return make_float2(a.x*b.x - a.y*b.y, a.x*b.y + a.y*b.x);
}

// async 16B global -> LDS (lane dest = uniform base + lane*16)
__device__ __forceinline__ void gload_lds16(void* lds, const void* g){
    __builtin_amdgcn_global_load_lds(
        (const __attribute__((address_space(1))) unsigned int*)g,
        (__attribute__((address_space(3))) unsigned int*)lds,
        16, 0, 0);
}

// ---------------------------------------------------------------------------
// Kernel 1: simulate circuit on basis state e_j (block j) and emit the
// 128x256 complex matrix W as two PLAIN row-major bf16 planes:
//   Wre[m][k] at W[m*256+k], Wim at W[32768 + m*256+k]   (128 KB total)
// ---------------------------------------------------------------------------
__global__ __launch_bounds__(256) void build_w_kernel(const float* __restrict__ params,
                                                      unsigned short* __restrict__ W){
    __shared__ float2 st[2][DIM];
    __shared__ float2 gm[NLAYERS*NQ][4];   // U0a,U0b,U1a,U1b per gate
    const int j = blockIdx.x;
    const int i = threadIdx.x;

    if (i < NLAYERS*NQ){
        const float* pp = params + i*3;
        float hx = 0.5f*pp[0], hy = 0.5f*pp[1], hz = 0.5f*pp[2];
        float cx = cosf(hx), sx = sinf(hx);
        float cy = cosf(hy), sy = sinf(hy);
        float cz = cosf(hz), sz = sinf(hz);
        float2 ezm = make_float2(cz, -sz), ezp = make_float2(cz, sz);
        float2 m00 = make_float2( cy*cx,  sy*sx);
        float2 m01 = make_float2(-sy*cx, -cy*sx);
        float2 m10 = make_float2( sy*cx, -cy*sx);
        float2 m11 = make_float2( cy*cx, -sy*sx);
        gm[i][0] = cmul(ezm, m00);
        gm[i][1] = cmul(ezm, m01);
        gm[i][2] = cmul(ezp, m10);
        gm[i][3] = cmul(ezp, m11);
    }

    // composed CNOT-ring permutation (params-independent, same all layers)
    int psrc = i;
    #pragma unroll
    for (int q = NQ-1; q >= 0; --q){
        int c  = 7 - q;
        int tb = 7 - ((q + 1) & 7);
        psrc = ((psrc >> c) & 1) ? (psrc ^ (1 << tb)) : psrc;
    }

    int cur = 0;
    st[0][i] = make_float2(i == j ? 1.0f : 0.0f, 0.0f);
    __syncthreads();

    for (int l = 0; l < NLAYERS; ++l){
        for (int q = 0; q < NQ; ++q){
            float2 U0a = gm[l*NQ+q][0], U0b = gm[l*NQ+q][1];
            float2 U1a = gm[l*NQ+q][2], U1b = gm[l*NQ+q][3];
            int p  = 7 - q;
            int bs = (i >> p) & 1;
            int i0 = i & ~(1 << p), i1 = i | (1 << p);
            float2 a0 = st[cur][i0], a1 = st[cur][i1];
            float2 ua = bs ? U1a : U0a;
            float2 ub = bs ? U1b : U0b;
            float2 r;
            r.x = ua.x*a0.x - ua.y*a0.y + ub.x*a1.x - ub.y*a1.y;
            r.y = ua.x*a0.y + ua.y*a0.x + ub.x*a1.y + ub.y*a1.x;
            st[cur ^ 1][i] = r;
            cur ^= 1;
            __syncthreads();
        }
        // fused CNOT ring
        float2 r = st[cur][psrc];
        st[cur ^ 1][i] = r;
        cur ^= 1;
        __syncthreads();
    }

    // column j of W: thread i<128 -> Wre[i][j], thread i>=128 -> Wim[i-128][j]
    const int m = i & 127;
    float2 a = st[cur][m];
    if (i < 128) W[(uint32_t)m*256u + (uint32_t)j]          = f2bf(a.x);
    else         W[32768u + (uint32_t)m*256u + (uint32_t)j] = f2bf(a.y);
}

// ---------------------------------------------------------------------------
// Kernel 2: out[m] = sum_j |sum_k W[j][k]*(sr[m][k] + i si[m][k])|^2
//
// Round-6: cut LDS read amplification 8x -> 4x.
//   - 1024 blocks x 256 threads (4 waves). 2 blocks/CU (64.3 KB LDS),
//     2 waves/SIMD -> 256 VGPR/wave budget.
//   - Waves split J in 32s: wave w owns j = w*32..w*32+31; B fragments
//     (2 jfrags x 8 ksteps x 2 planes x bf16x8 = 128 VGPRs) loaded once,
//     stay in registers. Accumulator = 2 C-frags x (R,I) = 16 regs.
//   - A shared by the 4 waves: 2 x 32 KB LDS double buffer staged via
//     global_load_lds (source-swizzled / read-deswizzled), counted
//     s_waitcnt vmcnt(8) -> DMA queue never drains in the loop
//     (8 KB/wave in flight).
//   - Race discipline (round-5 fix): explicit s_waitcnt lgkmcnt(0) before
//     the raw second barrier (red[] handoff + Abuf reuse).
// ---------------------------------------------------------------------------

#define STAGE(B) { \
    gload_lds16(&Abuf[B][(c0+0)*DIM], srcp0); srcp0 += 16*DIM; \
    gload_lds16(&Abuf[B][(c0+1)*DIM], srcp1); srcp1 += 16*DIM; \
    gload_lds16(&Abuf[B][(c0+2)*DIM], srcp2); srcp2 += 16*DIM; \
    gload_lds16(&Abuf[B][(c0+3)*DIM], srcp3); srcp3 += 16*DIM; \
    gload_lds16(&Abuf[B][(c0+4)*DIM], srcp4); srcp4 += 16*DIM; \
    gload_lds16(&Abuf[B][(c0+5)*DIM], srcp5); srcp5 += 16*DIM; \
    gload_lds16(&Abuf[B][(c0+6)*DIM], srcp6); srcp6 += 16*DIM; \
    gload_lds16(&Abuf[B][(c0+7)*DIM], srcp7); srcp7 += 16*DIM; }

#define LOADB(F, S) \
    const bf16x8 bre_##F##_##S = *(const bf16x8*)(wrp##F + S*32); \
    const bf16x8 bim_##F##_##S = *(const bf16x8*)(wrp##F + 32768 + S*32);

#define BSTEP(S) { \
    f32x4 ra0 = *(const f32x4*)(arow + S*32 + o0); \
    f32x4 ra1 = *(const f32x4*)(arow + S*32 + o1); \
    f32x4 qa0 = *(const f32x4*)(irow + S*32 + o0); \
    f32x4 qa1 = *(const f32x4*)(irow + S*32 + o1); \
    union { f32x4 v; uint32_t u[4]; } ha_, hb_; \
    union { uint32_t u[4]; bf16x8 f; } pr_, pi_, pn_; \
    ha_.v = ra0; hb_.v = ra1; \
    pr_.u[0] = __builtin_amdgcn_perm(ha_.u[1], ha_.u[0], 0x07060302); \
    pr_.u[1] = __builtin_amdgcn_perm(ha_.u[3], ha_.u[2], 0x07060302); \
    pr_.u[2] = __builtin_amdgcn_perm(hb_.u[1], hb_.u[0], 0x07060302); \
    pr_.u[3] = __builtin_amdgcn_perm(hb_.u[3], hb_.u[2], 0x07060302); \
    ha_.v = qa0; hb_.v = qa1; \
    pi_.u[0] = __builtin_amdgcn_perm(ha_.u[1], ha_.u[0], 0x07060302); \
    pi_.u[1] = __builtin_amdgcn_perm(ha_.u[3], ha_.u[2], 0x07060302); \
    pi_.u[2] = __builtin_amdgcn_perm(hb_.u[1], hb_.u[0], 0x07060302); \
    pi_.u[3] = __builtin_amdgcn_perm(hb_.u[3], hb_.u[2], 0x07060302); \
    pn_.u[0] = pi_.u[0] ^ 0x80008000u; \
    pn_.u[1] = pi_.u[1] ^ 0x80008000u; \
    pn_.u[2] = pi_.u[2] ^ 0x80008000u; \
    pn_.u[3] = pi_.u[3] ^ 0x80008000u; \
    const bf16x8 fr_ = pr_.f, fi_ = pi_.f, fn_ = pn_.f; \
    accR0 = __builtin_amdgcn_mfma_f32_16x16x32_bf16(fr_, bre_0_##S, accR0, 0, 0, 0); \
    accR0 = __builtin_amdgcn_mfma_f32_16x16x32_bf16(fn_, bim_0_##S, accR0, 0, 0, 0); \
    accI0 = __builtin_amdgcn_mfma_f32_16x16x32_bf16(fr_, bim_0_##S, accI0, 0, 0, 0); \
    accI0 = __builtin_amdgcn_mfma_f32_16x16x32_bf16(fi_, bre_0_##S, accI0, 0, 0, 0); \
    accR1 = __builtin_amdgcn_mfma_f32_16x16x32_bf16(fr_, bre_1_##S, accR1, 0, 0, 0); \
    accR1 = __builtin_amdgcn_mfma_f32_16x16x32_bf16(fn_, bim_1_##S, accR1, 0, 0, 0); \
    accI1 = __builtin_amdgcn_mfma_f32_16x16x32_bf16(fr_, bim_1_##S, accI1, 0, 0, 0); \
    accI1 = __builtin_amdgcn_mfma_f32_16x16x32_bf16(fi_, bre_1_##S, accI1, 0, 0, 0); \
}

__global__ __launch_bounds__(256, 2) void qform4_kernel(const float* __restrict__ sr,
                                                        const float* __restrict__ si,
                                                        const unsigned short* __restrict__ W,
                                                        float* __restrict__ out){
    __shared__ float Abuf[2][32*DIM];   // 2 x 32 KB A tile (16 sr rows + 16 si rows)
    __shared__ float red[64];           // 4 waves x 16 rows

    const int tid  = threadIdx.x;
    const int lane = tid & 63;
    const int w    = tid >> 6;        // 0..3  (j block w*32..w*32+31)
    const int l15  = lane & 15;
    const int quad = lane >> 4;       // 0..3
    const int x7   = l15 & 7;
    const size_t m0 = (size_t)blockIdx.x * 128;   // 128 rows per block, 8 tiles

    // ---- staging sources: wave w stages LDS rows c0..c0+7 of each tile.
    // LDS rows 0..15 = sr rows (tile_base+r), rows 16..31 = si rows.
    // Source granule pre-swizzled: lane l supplies granule (l ^ (row&7));
    // DMA writes linearly -> read side XORs it back out.
    const int c0 = w * 8;
    #define SRCP(I) ((((c0+I) < 16) ? sr : si) + (m0 + ((c0+I)&15))*DIM + ((lane ^ ((c0+I)&7)) << 2))
    const float* srcp0 = SRCP(0);
    const float* srcp1 = SRCP(1);
    const float* srcp2 = SRCP(2);
    const float* srcp3 = SRCP(3);
    const float* srcp4 = SRCP(4);
    const float* srcp5 = SRCP(5);
    const float* srcp6 = SRCP(6);
    const float* srcp7 = SRCP(7);
    #undef SRCP

    // prologue: stage tile 0 into buffer 0 (starts the HBM stream early)
    STAGE(0)

    // ---- B fragments in registers: wave w covers j = w*32 + F*16 + l15,
    // k = S*32 + quad*8..+7, both planes. 2F x 8S x 2 x bf16x8 = 128 VGPRs.
    const unsigned short* wrp0 = W + ((uint32_t)(w*32 +  0 + l15))*256u + (uint32_t)(quad*8);
    const unsigned short* wrp1 = W + ((uint32_t)(w*32 + 16 + l15))*256u + (uint32_t)(quad*8);
    LOADB(0,0) LOADB(0,1) LOADB(0,2) LOADB(0,3)
    LOADB(0,4) LOADB(0,5) LOADB(0,6) LOADB(0,7)
    LOADB(1,0) LOADB(1,1) LOADB(1,2) LOADB(1,3)
    LOADB(1,4) LOADB(1,5) LOADB(1,6) LOADB(1,7)

    // read-side swizzle offsets (float units): granule (quad*2+c) ^ x7
    const int o0 = (((quad << 1)    ) ^ x7) << 2;
    const int o1 = (((quad << 1) | 1) ^ x7) << 2;

    int buf = 0;
    #pragma unroll 1
    for (int t = 0; t < 8; ++t){
        if (t < 7){
            STAGE(buf ^ 1)
            // FIFO: waits tile-t DMA (and, on iter 0, the B loads) while
            // leaving the 8 just-issued next-tile loads in flight.
            asm volatile("s_waitcnt vmcnt(8)" ::: "memory");
        } else {
            asm volatile("s_waitcnt vmcnt(0)" ::: "memory");
        }
        __builtin_amdgcn_s_barrier();
        __builtin_amdgcn_sched_barrier(0);   // pin Abuf reads below barrier

        const float* arow = &Abuf[buf][l15 * DIM];          // sr row
        const float* irow = &Abuf[buf][(16 + l15) * DIM];   // si row

        f32x4 accR0 = {0.f,0.f,0.f,0.f}, accI0 = {0.f,0.f,0.f,0.f};
        f32x4 accR1 = {0.f,0.f,0.f,0.f}, accI1 = {0.f,0.f,0.f,0.f};
        BSTEP(0) BSTEP(1) BSTEP(2) BSTEP(3)
        BSTEP(4) BSTEP(5) BSTEP(6) BSTEP(7)

        // ---- reduce over this wave's 32 j's. C/D: row = quad*4+r, col = l15.
        #pragma unroll
        for (int r = 0; r < 4; ++r){
            const float v0 = accR0[r], u0 = accI0[r];
            const float v1 = accR1[r], u1 = accI1[r];
            float tt = v0*v0 + u0*u0 + v1*v1 + u1*u1;
            tt += __shfl_xor(tt, 1);
            tt += __shfl_xor(tt, 2);
            tt += __shfl_xor(tt, 4);
            tt += __shfl_xor(tt, 8);
            if (l15 == 0) red[w*16 + quad*4 + r] = tt;
        }
        // raw s_barrier does NOT drain lgkmcnt: drain red[] writes (and any
        // pending Abuf reads, protecting buffer reuse) explicitly.
        asm volatile("s_waitcnt lgkmcnt(0)" ::: "memory");
        __builtin_amdgcn_s_barrier();
        __builtin_amdgcn_sched_barrier(0);

        if (tid < 16){
            out[m0 + t*16 + tid] = red[tid] + red[16 + tid] + red[32 + tid] + red[48 + tid];
        }
        buf ^= 1;
    }
}

extern "C" void kernel_launch(void* const* d_in, const int* in_sizes, int n_in,
                              void* d_out, int out_size, void* d_ws, size_t ws_size,
                              hipStream_t stream){
    const float* params = (const float*)d_in[0];
    const float* sr     = (const float*)d_in[1];
    const float* si     = (const float*)d_in[2];
    unsigned short* Wimg = (unsigned short*)d_ws;   // 128 KB image
    float* out          = (float*)d_out;

    build_w_kernel<<<dim3(DIM), dim3(256), 0, stream>>>(params, Wimg);
    qform4_kernel<<<dim3(1024), dim3(256), 0, stream>>>(sr, si, Wimg, out);
}

// Round 8
// 297.362 us; speedup vs baseline: 1.0148x; 1.0148x over previous
//
#include <hip/hip_runtime.h>
#include <stdint.h>

#define NLAYERS 3
#define NQ 8
#define DIM 256          // 2^NQ
#define BATCH 131072

typedef float  f32x4  __attribute__((ext_vector_type(4)));
typedef __bf16 bf16x8 __attribute__((ext_vector_type(8)));

__device__ __forceinline__ unsigned short f2bf(float f){
    union { float f; uint32_t u; } v; v.f = f;
    uint32_t u = v.u;
    u += 0x7fffu + ((u >> 16) & 1u);   // round-to-nearest-even
    return (unsigned short)(u >> 16);
}

__device__ __forceinline__ float2 cmul(float2 a, float2 b){
    return make_float2(a.x*b.x - a.y*b.y, a.x*b.y + a.y*b.x);
}

// ---------------------------------------------------------------------------
// Kernel 1: simulate circuit on basis state e_j (block j) and emit the
// 128x256 complex matrix W as two PLAIN row-major bf16 planes:
//   Wre[m][k] at W[m*256+k], Wim at W[32768 + m*256+k]   (128 KB total)
// ---------------------------------------------------------------------------
__global__ __launch_bounds__(256) void build_w_kernel(const float* __restrict__ params,
                                                      unsigned short* __restrict__ W){
    __shared__ float2 st[2][DIM];
    __shared__ float2 gm[NLAYERS*NQ][4];   // U0a,U0b,U1a,U1b per gate
    const int j = blockIdx.x;
    const int i = threadIdx.x;

    if (i < NLAYERS*NQ){
        const float* pp = params + i*3;
        float hx = 0.5f*pp[0], hy = 0.5f*pp[1], hz = 0.5f*pp[2];
        float cx = cosf(hx), sx = sinf(hx);
        float cy = cosf(hy), sy = sinf(hy);
        float cz = cosf(hz), sz = sinf(hz);
        float2 ezm = make_float2(cz, -sz), ezp = make_float2(cz, sz);
        float2 m00 = make_float2( cy*cx,  sy*sx);
        float2 m01 = make_float2(-sy*cx, -cy*sx);
        float2 m10 = make_float2( sy*cx, -cy*sx);
        float2 m11 = make_float2( cy*cx, -sy*sx);
        gm[i][0] = cmul(ezm, m00);
        gm[i][1] = cmul(ezm, m01);
        gm[i][2] = cmul(ezp, m10);
        gm[i][3] = cmul(ezp, m11);
    }

    // composed CNOT-ring permutation (params-independent, same all layers)
    int psrc = i;
    #pragma unroll
    for (int q = NQ-1; q >= 0; --q){
        int c  = 7 - q;
        int tb = 7 - ((q + 1) & 7);
        psrc = ((psrc >> c) & 1) ? (psrc ^ (1 << tb)) : psrc;
    }

    int cur = 0;
    st[0][i] = make_float2(i == j ? 1.0f : 0.0f, 0.0f);
    __syncthreads();

    for (int l = 0; l < NLAYERS; ++l){
        for (int q = 0; q < NQ; ++q){
            float2 U0a = gm[l*NQ+q][0], U0b = gm[l*NQ+q][1];
            float2 U1a = gm[l*NQ+q][2], U1b = gm[l*NQ+q][3];
            int p  = 7 - q;
            int bs = (i >> p) & 1;
            int i0 = i & ~(1 << p), i1 = i | (1 << p);
            float2 a0 = st[cur][i0], a1 = st[cur][i1];
            float2 ua = bs ? U1a : U0a;
            float2 ub = bs ? U1b : U0b;
            float2 r;
            r.x = ua.x*a0.x - ua.y*a0.y + ub.x*a1.x - ub.y*a1.y;
            r.y = ua.x*a0.y + ua.y*a0.x + ub.x*a1.y + ub.y*a1.x;
            st[cur ^ 1][i] = r;
            cur ^= 1;
            __syncthreads();
        }
        // fused CNOT ring
        float2 r = st[cur][psrc];
        st[cur ^ 1][i] = r;
        cur ^= 1;
        __syncthreads();
    }

    // column j of W: thread i<128 -> Wre[i][j], thread i>=128 -> Wim[i-128][j]
    const int m = i & 127;
    float2 a = st[cur][m];
    if (i < 128) W[(uint32_t)m*256u + (uint32_t)j]          = f2bf(a.x);
    else         W[32768u + (uint32_t)m*256u + (uint32_t)j] = f2bf(a.y);
}

// ---------------------------------------------------------------------------
// Kernel 2: out[m] = sum_j |sum_k W[j][k]*(sr[m][k] + i si[m][k])|^2
//
// Round-7/8 A/B vs round 6: ONLY the A-staging path changed.
//   global_load_lds DMA (capped ~1.2 TB/s on cold streams, rounds 0/5/6)
//   -> T14 register staging: global_load_dwordx4 into named regs (issued a
//   full tile ahead, 8 KB/wave in the plain VMEM queue, which rounds 2/3
//   demonstrated sustains >=2.9 TB/s), then vmcnt(0) + ds_write_b128 after
//   the compute phase. One raw barrier per tile (lgkmcnt-drained); red[]
//   double-buffered so the post-barrier out-store cannot race the next
//   tile's reduce.
//   Geometry unchanged: 1024 blocks x 256 threads (4 waves, J=32/wave,
//   B fragments in 128 VGPRs), 2 blocks/CU, 64.5 KB LDS.
// ---------------------------------------------------------------------------

#define STAGE_ISSUE() { \
    g0 = *(const f32x4*)srcp0; srcp0 += 16*DIM; \
    g1 = *(const f32x4*)srcp1; srcp1 += 16*DIM; \
    g2 = *(const f32x4*)srcp2; srcp2 += 16*DIM; \
    g3 = *(const f32x4*)srcp3; srcp3 += 16*DIM; \
    g4 = *(const f32x4*)srcp4; srcp4 += 16*DIM; \
    g5 = *(const f32x4*)srcp5; srcp5 += 16*DIM; \
    g6 = *(const f32x4*)srcp6; srcp6 += 16*DIM; \
    g7 = *(const f32x4*)srcp7; srcp7 += 16*DIM; }

// lane writes its 16 B at linear slot lane*16 (same layout the DMA produced)
#define DSWRITE(B) { \
    *(f32x4*)(&Abuf[B][(c0+0)*DIM + (lane<<2)]) = g0; \
    *(f32x4*)(&Abuf[B][(c0+1)*DIM + (lane<<2)]) = g1; \
    *(f32x4*)(&Abuf[B][(c0+2)*DIM + (lane<<2)]) = g2; \
    *(f32x4*)(&Abuf[B][(c0+3)*DIM + (lane<<2)]) = g3; \
    *(f32x4*)(&Abuf[B][(c0+4)*DIM + (lane<<2)]) = g4; \
    *(f32x4*)(&Abuf[B][(c0+5)*DIM + (lane<<2)]) = g5; \
    *(f32x4*)(&Abuf[B][(c0+6)*DIM + (lane<<2)]) = g6; \
    *(f32x4*)(&Abuf[B][(c0+7)*DIM + (lane<<2)]) = g7; }

#define LOADB(F, S) \
    const bf16x8 bre_##F##_##S = *(const bf16x8*)(wrp##F + S*32); \
    const bf16x8 bim_##F##_##S = *(const bf16x8*)(wrp##F + 32768 + S*32);

#define BSTEP(S) { \
    f32x4 ra0 = *(const f32x4*)(arow + S*32 + o0); \
    f32x4 ra1 = *(const f32x4*)(arow + S*32 + o1); \
    f32x4 qa0 = *(const f32x4*)(irow + S*32 + o0); \
    f32x4 qa1 = *(const f32x4*)(irow + S*32 + o1); \
    union { f32x4 v; uint32_t u[4]; } ha_, hb_; \
    union { uint32_t u[4]; bf16x8 f; } pr_, pi_, pn_; \
    ha_.v = ra0; hb_.v = ra1; \
    pr_.u[0] = __builtin_amdgcn_perm(ha_.u[1], ha_.u[0], 0x07060302); \
    pr_.u[1] = __builtin_amdgcn_perm(ha_.u[3], ha_.u[2], 0x07060302); \
    pr_.u[2] = __builtin_amdgcn_perm(hb_.u[1], hb_.u[0], 0x07060302); \
    pr_.u[3] = __builtin_amdgcn_perm(hb_.u[3], hb_.u[2], 0x07060302); \
    ha_.v = qa0; hb_.v = qa1; \
    pi_.u[0] = __builtin_amdgcn_perm(ha_.u[1], ha_.u[0], 0x07060302); \
    pi_.u[1] = __builtin_amdgcn_perm(ha_.u[3], ha_.u[2], 0x07060302); \
    pi_.u[2] = __builtin_amdgcn_perm(hb_.u[1], hb_.u[0], 0x07060302); \
    pi_.u[3] = __builtin_amdgcn_perm(hb_.u[3], hb_.u[2], 0x07060302); \
    pn_.u[0] = pi_.u[0] ^ 0x80008000u; \
    pn_.u[1] = pi_.u[1] ^ 0x80008000u; \
    pn_.u[2] = pi_.u[2] ^ 0x80008000u; \
    pn_.u[3] = pi_.u[3] ^ 0x80008000u; \
    const bf16x8 fr_ = pr_.f, fi_ = pi_.f, fn_ = pn_.f; \
    accR0 = __builtin_amdgcn_mfma_f32_16x16x32_bf16(fr_, bre_0_##S, accR0, 0, 0, 0); \
    accR0 = __builtin_amdgcn_mfma_f32_16x16x32_bf16(fn_, bim_0_##S, accR0, 0, 0, 0); \
    accI0 = __builtin_amdgcn_mfma_f32_16x16x32_bf16(fr_, bim_0_##S, accI0, 0, 0, 0); \
    accI0 = __builtin_amdgcn_mfma_f32_16x16x32_bf16(fi_, bre_0_##S, accI0, 0, 0, 0); \
    accR1 = __builtin_amdgcn_mfma_f32_16x16x32_bf16(fr_, bre_1_##S, accR1, 0, 0, 0); \
    accR1 = __builtin_amdgcn_mfma_f32_16x16x32_bf16(fn_, bim_1_##S, accR1, 0, 0, 0); \
    accI1 = __builtin_amdgcn_mfma_f32_16x16x32_bf16(fr_, bim_1_##S, accI1, 0, 0, 0); \
    accI1 = __builtin_amdgcn_mfma_f32_16x16x32_bf16(fi_, bre_1_##S, accI1, 0, 0, 0); \
}

__global__ __launch_bounds__(256, 2) void qform5_kernel(const float* __restrict__ sr,
                                                        const float* __restrict__ si,
                                                        const unsigned short* __restrict__ W,
                                                        float* __restrict__ out){
    __shared__ float Abuf[2][32*DIM];   // 2 x 32 KB A tile (16 sr rows + 16 si rows)
    __shared__ float red[2][64];        // double-buffered: 4 waves x 16 rows

    const int tid  = threadIdx.x;
    const int lane = tid & 63;
    const int w    = tid >> 6;        // 0..3  (j block w*32..w*32+31)
    const int l15  = lane & 15;
    const int quad = lane >> 4;       // 0..3
    const int x7   = l15 & 7;
    const size_t m0 = (size_t)blockIdx.x * 128;   // 128 rows per block, 8 tiles

    // ---- staging sources: wave w stages LDS rows c0..c0+7 of each tile.
    // LDS rows 0..15 = sr rows (tile_base+r), rows 16..31 = si rows.
    // Source granule pre-swizzled: lane l supplies granule (l ^ (row&7));
    // the write lands linearly at slot l -> read side XORs it back out.
    const int c0 = w * 8;
    #define SRCP(I) ((((c0+I) < 16) ? sr : si) + (m0 + ((c0+I)&15))*DIM + ((lane ^ ((c0+I)&7)) << 2))
    const float* srcp0 = SRCP(0);
    const float* srcp1 = SRCP(1);
    const float* srcp2 = SRCP(2);
    const float* srcp3 = SRCP(3);
    const float* srcp4 = SRCP(4);
    const float* srcp5 = SRCP(5);
    const float* srcp6 = SRCP(6);
    const float* srcp7 = SRCP(7);
    #undef SRCP

    // staging registers: one tile (8 x 16 B per lane = 32 VGPRs)
    f32x4 g0, g1, g2, g3, g4, g5, g6, g7;

    // ---- B fragments in registers: wave w covers j = w*32 + F*16 + l15,
    // k = S*32 + quad*8..+7, both planes. 2F x 8S x 2 x bf16x8 = 128 regs.
    const unsigned short* wrp0 = W + ((uint32_t)(w*32 +  0 + l15))*256u + (uint32_t)(quad*8);
    const unsigned short* wrp1 = W + ((uint32_t)(w*32 + 16 + l15))*256u + (uint32_t)(quad*8);
    LOADB(0,0) LOADB(0,1) LOADB(0,2) LOADB(0,3)
    LOADB(0,4) LOADB(0,5) LOADB(0,6) LOADB(0,7)
    LOADB(1,0) LOADB(1,1) LOADB(1,2) LOADB(1,3)
    LOADB(1,4) LOADB(1,5) LOADB(1,6) LOADB(1,7)

    // ---- prologue: tile 0 -> regs -> LDS[0]; issue tile 1; one raw barrier
    STAGE_ISSUE()                                     // tile 0
    asm volatile("s_waitcnt vmcnt(0)" ::: "memory");  // tile 0 + B frags home
    DSWRITE(0)
    STAGE_ISSUE()                                     // tile 1 (in flight)
    asm volatile("s_waitcnt lgkmcnt(0)" ::: "memory");
    __builtin_amdgcn_s_barrier();
    __builtin_amdgcn_sched_barrier(0);

    // read-side swizzle offsets (float units): granule (quad*2+c) ^ x7
    const int o0 = (((quad << 1)    ) ^ x7) << 2;
    const int o1 = (((quad << 1) | 1) ^ x7) << 2;

    int buf = 0;
    #pragma unroll 1
    for (int t = 0; t < 8; ++t){
        const float* arow = &Abuf[buf][l15 * DIM];          // sr row
        const float* irow = &Abuf[buf][(16 + l15) * DIM];   // si row

        f32x4 accR0 = {0.f,0.f,0.f,0.f}, accI0 = {0.f,0.f,0.f,0.f};
        f32x4 accR1 = {0.f,0.f,0.f,0.f}, accI1 = {0.f,0.f,0.f,0.f};
        BSTEP(0) BSTEP(1) BSTEP(2) BSTEP(3)
        BSTEP(4) BSTEP(5) BSTEP(6) BSTEP(7)

        // ---- reduce over this wave's 32 j's. C/D: row = quad*4+r, col = l15.
        #pragma unroll
        for (int r = 0; r < 4; ++r){
            const float v0 = accR0[r], u0 = accI0[r];
            const float v1 = accR1[r], u1 = accI1[r];
            float tt = v0*v0 + u0*u0 + v1*v1 + u1*u1;
            tt += __shfl_xor(tt, 1);
            tt += __shfl_xor(tt, 2);
            tt += __shfl_xor(tt, 4);
            tt += __shfl_xor(tt, 8);
            if (l15 == 0) red[t & 1][w*16 + quad*4 + r] = tt;
        }

        if (t < 7){
            // tile t+1 regs have been in flight across this whole compute
            asm volatile("s_waitcnt vmcnt(0)" ::: "memory");
            DSWRITE(buf ^ 1)                 // buf^1 consumed 2 barriers ago
            if (t < 6) STAGE_ISSUE()         // tile t+2 (DS reads g* at issue
                                             // before the loads rewrite them)
        }
        // raw s_barrier does NOT drain lgkmcnt: drain red[] + Abuf ds_writes
        asm volatile("s_waitcnt lgkmcnt(0)" ::: "memory");
        __builtin_amdgcn_s_barrier();
        __builtin_amdgcn_sched_barrier(0);

        if (tid < 16){
            const float* rd = red[t & 1];
            out[m0 + t*16 + tid] = rd[tid] + rd[16 + tid] + rd[32 + tid] + rd[48 + tid];
        }
        buf ^= 1;
    }
}

extern "C" void kernel_launch(void* const* d_in, const int* in_sizes, int n_in,
                              void* d_out, int out_size, void* d_ws, size_t ws_size,
                              hipStream_t stream){
    const float* params = (const float*)d_in[0];
    const float* sr     = (const float*)d_in[1];
    const float* si     = (const float*)d_in[2];
    unsigned short* Wimg = (unsigned short*)d_ws;   // 128 KB image
    float* out          = (float*)d_out;

    build_w_kernel<<<dim3(DIM), dim3(256), 0, stream>>>(params, Wimg);
    qform5_kernel<<<dim3(1024), dim3(256), 0, stream>>>(sr, si, Wimg, out);
}